// Round 2
// baseline (1714.166 us; speedup 1.0000x reference)
//
#include <hip/hip_runtime.h>
#include <cstddef>
#include <cstdint>

// Problem constants (from reference): B=256, T=512, I=128, H=64, 4H=256.
#define NB 256
#define NT 512
#define H4 256

typedef float v2f __attribute__((ext_vector_type(2)));

__device__ __forceinline__ float sigmoid_f(float x) {
    return 1.f / (1.f + __expf(-x));
}
__device__ __forceinline__ float tanh_f(float x) {
    return 2.f / (1.f + __expf(-2.f * x)) - 1.f;
}

// ---------------------------------------------------------------------------
// Transpose W [256, K] -> Wt [K, 256] (tiny, once per layer)
// ---------------------------------------------------------------------------
__global__ void transpose_w(const float* __restrict__ W, float* __restrict__ Wt, int K) {
    int idx = blockIdx.x * 256 + threadIdx.x;
    if (idx < 256 * K) {
        int n = idx / K, k = idx - n * K;
        Wt[k * 256 + n] = W[idx];
    }
}

// ---------------------------------------------------------------------------
// Input-projection GEMM: XP[m][n] = sum_k X[m][k]*Wt[k][n] + b1[n] + b2[n]
// M = B*T = 131072, N = 256, K = 128 or 64. (unchanged from round 1)
// ---------------------------------------------------------------------------
template <int K>
__global__ __launch_bounds__(256) void gemm_xp(
    const float* __restrict__ X, const float* __restrict__ Wt,
    const float* __restrict__ b1, const float* __restrict__ b2,
    float* __restrict__ XP)
{
    constexpr int TM = 64;
    constexpr int KC = 16;
    __shared__ __align__(16) float xT[K][TM + 4];
    __shared__ __align__(16) float wc[KC][256];
    const int m0 = blockIdx.x * TM;
    const int t  = threadIdx.x;
    const int cg = (t & 63) * 4;
    const int rg = (t >> 6) * 16;

    for (int idx = t; idx < TM * K; idx += 256) {
        int r = idx / K, k = idx - r * K;
        xT[k][r] = X[(size_t)(m0 + r) * K + k];
    }

    float acc[16][4];
    #pragma unroll
    for (int i = 0; i < 16; ++i)
        #pragma unroll
        for (int j = 0; j < 4; ++j) acc[i][j] = 0.f;

    for (int kc = 0; kc < K; kc += KC) {
        __syncthreads();
        #pragma unroll
        for (int i = 0; i < 4; ++i) {
            int e4 = (t + i * 256) * 4;
            int k = e4 >> 8, n = e4 & 255;
            *(float4*)&wc[k][n] = *(const float4*)&Wt[(size_t)(kc + k) * 256 + n];
        }
        __syncthreads();
        #pragma unroll
        for (int k = 0; k < KC; ++k) {
            float4 w = *(const float4*)&wc[k][cg];
            float xr[16];
            #pragma unroll
            for (int q = 0; q < 4; ++q)
                *(float4*)&xr[q * 4] = *(const float4*)&xT[kc + k][rg + q * 4];
            #pragma unroll
            for (int rr = 0; rr < 16; ++rr) {
                acc[rr][0] += xr[rr] * w.x;
                acc[rr][1] += xr[rr] * w.y;
                acc[rr][2] += xr[rr] * w.z;
                acc[rr][3] += xr[rr] * w.w;
            }
        }
    }

    float bias[4];
    #pragma unroll
    for (int j = 0; j < 4; ++j) bias[j] = b1[cg + j] + b2[cg + j];
    #pragma unroll
    for (int rr = 0; rr < 16; ++rr) {
        float4 o;
        o.x = acc[rr][0] + bias[0];
        o.y = acc[rr][1] + bias[1];
        o.z = acc[rr][2] + bias[2];
        o.w = acc[rr][3] + bias[3];
        *(float4*)&XP[(size_t)(m0 + rg + rr) * 256 + cg] = o;
    }
}

// ---------------------------------------------------------------------------
// LSTM scan v2: ONE WAVE per batch element, ZERO barriers.
// Lane j owns h[j], c[j], and the four W_hh rows {j, 64+j, 128+j, 192+j}
// in registers (256 VGPRs, float2-packed for v_pk_fma_f32).
// Per step: ds_write h[j] -> 16 broadcast ds_read_b128 -> 128 pk-FMA ->
// lane-local activations + cell update. No __syncthreads -> no vmcnt(0)
// drain; xp is register-prefetched 3 steps deep (counted vmcnt waits).
// ---------------------------------------------------------------------------
__global__ __launch_bounds__(64, 1) void lstm_scan_wave(
    const float* __restrict__ xp,    // [B*T, 256]
    const float* __restrict__ Whh,   // [256, 64] row-major
    float* __restrict__ hout,        // write_all: [B*T, 64]; else [B, 64]
    int write_all)
{
    const int b = blockIdx.x;
    const int j = threadIdx.x & 63;
    __shared__ __align__(16) float hb[64];

    // Per-lane weight rows as float2 (one-time, L2-served: W_hh is 64 KB)
    v2f w0[32], w1[32], w2g[32], w3[32];
    {
        const v2f* Wv = (const v2f*)Whh;
        const int r0 = j * 32, r1 = (64 + j) * 32,
                  r2 = (128 + j) * 32, r3 = (192 + j) * 32;
        #pragma unroll
        for (int q = 0; q < 32; ++q) {
            w0[q]  = Wv[r0 + q];
            w1[q]  = Wv[r1 + q];
            w2g[q] = Wv[r2 + q];
            w3[q]  = Wv[r3 + q];
        }
    }

    const float* xpb = xp + (size_t)b * NT * H4 + j;
    #define XPLD(dst, tt) do { const float* _p = xpb + (size_t)(tt) * H4; \
        dst[0] = _p[0]; dst[1] = _p[64]; dst[2] = _p[128]; dst[3] = _p[192]; } while (0)

    float xc[4], xn1[4], xn2[4];
    XPLD(xc, 0); XPLD(xn1, 1); XPLD(xn2, 2);

    float c = 0.f, h = 0.f;
    hb[j] = 0.f;

    for (int t = 0; t < NT; ++t) {
        // ---- matvec: gates = W_hh . h  (h broadcast from LDS) ----
        const v2f* hv = (const v2f*)hb;
        v2f a0 = {0.f, 0.f}, b0 = {0.f, 0.f};
        v2f a1 = {0.f, 0.f}, b1 = {0.f, 0.f};
        v2f a2 = {0.f, 0.f}, b2 = {0.f, 0.f};
        v2f a3 = {0.f, 0.f}, b3 = {0.f, 0.f};
        #pragma unroll
        for (int q = 0; q < 32; q += 2) {
            v2f h0 = hv[q], h1 = hv[q + 1];      // one ds_read_b128 (broadcast)
            a0 += w0[q] * h0;   b0 += w0[q + 1] * h1;
            a1 += w1[q] * h0;   b1 += w1[q + 1] * h1;
            a2 += w2g[q] * h0;  b2 += w2g[q + 1] * h1;
            a3 += w3[q] * h0;   b3 += w3[q + 1] * h1;
        }
        float p0 = xc[0] + ((a0.x + a0.y) + (b0.x + b0.y));
        float p1 = xc[1] + ((a1.x + a1.y) + (b1.x + b1.y));
        float p2 = xc[2] + ((a2.x + a2.y) + (b2.x + b2.y));
        float p3 = xc[3] + ((a3.x + a3.y) + (b3.x + b3.y));

        // ---- lane-local activations + cell update (no divergence) ----
        float iv = sigmoid_f(p0);
        float fv = sigmoid_f(p1);
        float gv = tanh_f(p2);
        float ov = sigmoid_f(p3);
        c = fv * c + iv * gv;
        h = ov * tanh_f(c);

        hb[j] = h;                                // next step's broadcast source
        if (write_all)
            hout[((size_t)b * NT + t) * 64 + j] = h;

        // ---- rotate register prefetch (depth 3) ----
        #pragma unroll
        for (int u = 0; u < 4; ++u) { xc[u] = xn1[u]; xn1[u] = xn2[u]; }
        int tn = t + 3; if (tn > NT - 1) tn = NT - 1;
        XPLD(xn2, tn);
    }
    if (!write_all)
        hout[(size_t)b * 64 + j] = h;
    #undef XPLD
}

// ---------------------------------------------------------------------------
// Final linear: out[b][o] = b_out[o] + sum_j h_last[b][j] * W_out[o][j]
// ---------------------------------------------------------------------------
__global__ __launch_bounds__(256) void final_linear(
    const float* __restrict__ hl,    // [256, 64]
    const float* __restrict__ Wout,  // [2, 64]
    const float* __restrict__ bout,  // [2]
    float* __restrict__ out)         // [256, 2]
{
    __shared__ float w[128];
    int t = threadIdx.x;
    if (t < 128) w[t] = Wout[t];
    __syncthreads();
    const float* h = hl + (size_t)t * 64;
    float a0 = bout[0], a1 = bout[1];
    #pragma unroll 8
    for (int j = 0; j < 64; ++j) {
        float hv = h[j];
        a0 += hv * w[j];
        a1 += hv * w[64 + j];
    }
    out[t * 2 + 0] = a0;
    out[t * 2 + 1] = a1;
}

// ---------------------------------------------------------------------------
extern "C" void kernel_launch(void* const* d_in, const int* in_sizes, int n_in,
                              void* d_out, int out_size, void* d_ws, size_t ws_size,
                              hipStream_t stream)
{
    const float* x     = (const float*)d_in[0];
    const float* W_ih0 = (const float*)d_in[1];
    const float* W_hh0 = (const float*)d_in[2];
    const float* b_ih0 = (const float*)d_in[3];
    const float* b_hh0 = (const float*)d_in[4];
    const float* W_ih1 = (const float*)d_in[5];
    const float* W_hh1 = (const float*)d_in[6];
    const float* b_ih1 = (const float*)d_in[7];
    const float* b_hh1 = (const float*)d_in[8];
    const float* W_ih2 = (const float*)d_in[9];
    const float* W_hh2 = (const float*)d_in[10];
    const float* b_ih2 = (const float*)d_in[11];
    const float* b_hh2 = (const float*)d_in[12];
    const float* W_out = (const float*)d_in[13];
    const float* b_out = (const float*)d_in[14];
    float* out = (float*)d_out;

    const size_t M = (size_t)NB * NT;              // 131072
    const size_t XP_BYTES  = M * H4 * sizeof(float);   // 128 MiB
    const size_t HA_BYTES  = M * 64 * sizeof(float);   // 32 MiB
    const size_t WT0_BYTES = 128 * 256 * sizeof(float);
    const size_t WT1_BYTES = 64 * 256 * sizeof(float);
    const size_t WT2_BYTES = 64 * 256 * sizeof(float);
    const size_t HL_BYTES  = NB * 64 * sizeof(float);
    if (ws_size < XP_BYTES + HA_BYTES + WT0_BYTES + WT1_BYTES + WT2_BYTES + HL_BYTES)
        return;

    char* ws = (char*)d_ws;
    float* XP  = (float*)ws;
    float* HA  = (float*)(ws + XP_BYTES);
    float* WT0 = (float*)(ws + XP_BYTES + HA_BYTES);
    float* WT1 = WT0 + 128 * 256;
    float* WT2 = WT1 + 64 * 256;
    float* HL  = WT2 + 64 * 256;

    transpose_w<<<128, 256, 0, stream>>>(W_ih0, WT0, 128);
    transpose_w<<<64, 256, 0, stream>>>(W_ih1, WT1, 64);
    transpose_w<<<64, 256, 0, stream>>>(W_ih2, WT2, 64);

    const int ngrid = (int)(M / 64);   // 2048

    // Layer 0
    gemm_xp<128><<<ngrid, 256, 0, stream>>>(x, WT0, b_ih0, b_hh0, XP);
    lstm_scan_wave<<<NB, 64, 0, stream>>>(XP, W_hh0, HA, 1);
    // Layer 1
    gemm_xp<64><<<ngrid, 256, 0, stream>>>(HA, WT1, b_ih1, b_hh1, XP);
    lstm_scan_wave<<<NB, 64, 0, stream>>>(XP, W_hh1, HA, 1);
    // Layer 2 (only last h needed downstream)
    gemm_xp<64><<<ngrid, 256, 0, stream>>>(HA, WT2, b_ih2, b_hh2, XP);
    lstm_scan_wave<<<NB, 64, 0, stream>>>(XP, W_hh2, HL, 0);
    // Final projection
    final_linear<<<1, 256, 0, stream>>>(HL, W_out, b_out, out);
}

// Round 3
// 1012.750 us; speedup vs baseline: 1.6926x; 1.6926x over previous
//
#include <hip/hip_runtime.h>
#include <cstddef>
#include <cstdint>

// Problem constants (from reference): B=256, T=512, I=128, H=64, 4H=256.
#define NB 256
#define NT 512
#define H4 256

typedef float v2f __attribute__((ext_vector_type(2)));

__device__ __forceinline__ float sigmoid_f(float x) {
    return 1.f / (1.f + __expf(-x));
}
__device__ __forceinline__ float tanh_f(float x) {
    return 2.f / (1.f + __expf(-2.f * x)) - 1.f;
}

// select val(k) where x_m = val(g^m): returns x[m] for runtime m (2-level cndmask)
__device__ __forceinline__ float sel4(float x0, float x1, float x2, float x3, int m) {
    float lo = (m & 1) ? x1 : x0;
    float hi = (m & 1) ? x3 : x2;
    return (m & 2) ? hi : lo;
}

// ---------------------------------------------------------------------------
// Transpose W [256, K] -> Wt [K, 256] (tiny, once per layer)
// ---------------------------------------------------------------------------
__global__ void transpose_w(const float* __restrict__ W, float* __restrict__ Wt, int K) {
    int idx = blockIdx.x * 256 + threadIdx.x;
    if (idx < 256 * K) {
        int n = idx / K, k = idx - n * K;
        Wt[k * 256 + n] = W[idx];
    }
}

// ---------------------------------------------------------------------------
// Input-projection GEMM: XP[m][n] = sum_k X[m][k]*Wt[k][n] + b1[n] + b2[n]
// (unchanged from round 1 — isolate the scan change)
// ---------------------------------------------------------------------------
template <int K>
__global__ __launch_bounds__(256) void gemm_xp(
    const float* __restrict__ X, const float* __restrict__ Wt,
    const float* __restrict__ b1, const float* __restrict__ b2,
    float* __restrict__ XP)
{
    constexpr int TM = 64;
    constexpr int KC = 16;
    __shared__ __align__(16) float xT[K][TM + 4];
    __shared__ __align__(16) float wc[KC][256];
    const int m0 = blockIdx.x * TM;
    const int t  = threadIdx.x;
    const int cg = (t & 63) * 4;
    const int rg = (t >> 6) * 16;

    for (int idx = t; idx < TM * K; idx += 256) {
        int r = idx / K, k = idx - r * K;
        xT[k][r] = X[(size_t)(m0 + r) * K + k];
    }

    float acc[16][4];
    #pragma unroll
    for (int i = 0; i < 16; ++i)
        #pragma unroll
        for (int j = 0; j < 4; ++j) acc[i][j] = 0.f;

    for (int kc = 0; kc < K; kc += KC) {
        __syncthreads();
        #pragma unroll
        for (int i = 0; i < 4; ++i) {
            int e4 = (t + i * 256) * 4;
            int k = e4 >> 8, n = e4 & 255;
            *(float4*)&wc[k][n] = *(const float4*)&Wt[(size_t)(kc + k) * 256 + n];
        }
        __syncthreads();
        #pragma unroll
        for (int k = 0; k < KC; ++k) {
            float4 w = *(const float4*)&wc[k][cg];
            float xr[16];
            #pragma unroll
            for (int q = 0; q < 4; ++q)
                *(float4*)&xr[q * 4] = *(const float4*)&xT[kc + k][rg + q * 4];
            #pragma unroll
            for (int rr = 0; rr < 16; ++rr) {
                acc[rr][0] += xr[rr] * w.x;
                acc[rr][1] += xr[rr] * w.y;
                acc[rr][2] += xr[rr] * w.z;
                acc[rr][3] += xr[rr] * w.w;
            }
        }
    }

    float bias[4];
    #pragma unroll
    for (int j = 0; j < 4; ++j) bias[j] = b1[cg + j] + b2[cg + j];
    #pragma unroll
    for (int rr = 0; rr < 16; ++rr) {
        float4 o;
        o.x = acc[rr][0] + bias[0];
        o.y = acc[rr][1] + bias[1];
        o.z = acc[rr][2] + bias[2];
        o.w = acc[rr][3] + bias[3];
        *(float4*)&XP[(size_t)(m0 + rg + rr) * 256 + cg] = o;
    }
}

// ---------------------------------------------------------------------------
// LSTM scan v3: 4 waves/block (one block per batch element).
// Lane layout: gate g = tid&3, unit u = tid>>2 (the 4 gate-lanes of a unit
// are adjacent and in the same wave -> gate exchange via __shfl_xor, no LDS,
// no barrier). Each lane holds ONE W_hh row (64 weights = 32 v2f, fits).
// h broadcast via double-buffered hbuf[2][64]; ONE raw s_barrier per step
// with explicit lgkmcnt(0) only -> xp register prefetch (depth 4) and h
// stores stay in flight across barriers (no vmcnt drain).
// Cell update is redundant in all 4 gate-lanes (identical bits); only the
// g==0 lane writes hbuf / global h.
// ---------------------------------------------------------------------------
__global__ __launch_bounds__(256) void lstm_scan_shfl(
    const float* __restrict__ xp,    // [B*T, 256] gate-major columns
    const float* __restrict__ Whh,   // [256, 64] row-major
    float* __restrict__ hout,        // write_all: [B*T, 64]; else [B, 64]
    int write_all)
{
    const int tid = threadIdx.x;
    const int b = blockIdx.x;
    const int g = tid & 3;
    const int u = tid >> 2;            // 0..63
    __shared__ __align__(16) float hbuf[2][64];

    // One W_hh row per lane: row = g*64 + u (PyTorch gate order i,f,g,o)
    v2f wr[32];
    {
        const v2f* Wv = (const v2f*)(Whh + (size_t)(g * 64 + u) * 64);
        #pragma unroll
        for (int q = 0; q < 32; ++q) wr[q] = Wv[q];
    }

    if (tid < 64) hbuf[0][tid] = 0.f;
    asm volatile("s_waitcnt lgkmcnt(0)" ::: "memory");
    __builtin_amdgcn_s_barrier();
    __builtin_amdgcn_sched_barrier(0);

    const float* xpb = xp + (size_t)b * NT * H4 + (g * 64 + u);
    float xr[4];
    #pragma unroll
    for (int d = 0; d < 4; ++d) xr[d] = xpb[(size_t)d * H4];

    float* hob = hout + (write_all ? ((size_t)b * NT * 64 + u)
                                   : ((size_t)b * 64 + u));
    const bool writer = (g == 0);

    float c = 0.f, h = 0.f;

    #pragma unroll 4
    for (int t = 0; t < NT; ++t) {
        // ---- matvec: pre = W_hh[row] . h_{t-1} (broadcast LDS reads) ----
        const v2f* hv = (const v2f*)hbuf[t & 1];
        v2f a0 = {0.f, 0.f}, a1 = {0.f, 0.f}, a2 = {0.f, 0.f}, a3 = {0.f, 0.f};
        #pragma unroll
        for (int q = 0; q < 32; q += 4) {
            a0 += wr[q + 0] * hv[q + 0];
            a1 += wr[q + 1] * hv[q + 1];
            a2 += wr[q + 2] * hv[q + 2];
            a3 += wr[q + 3] * hv[q + 3];
        }
        v2f aa = (a0 + a1) + (a2 + a3);
        float pre = xr[t & 3] + aa.x + aa.y;

        // refill the just-consumed prefetch slot (t+4), clamped at tail
        { int tn = t + 4; if (tn > NT - 1) tn = NT - 1;
          xr[t & 3] = xpb[(size_t)tn * H4]; }

        // ---- activation (wave-uniform per-lane gate type) ----
        float p = (g == 2) ? tanh_f(pre) : sigmoid_f(pre);

        // ---- gate exchange within the 4-lane unit group ----
        float x1 = __shfl_xor(p, 1, 64);
        float x2 = __shfl_xor(p, 2, 64);
        float x3 = __shfl_xor(x1, 2, 64);   // val(g^3)
        float iv = sel4(p, x1, x2, x3, g);
        float fv = sel4(p, x1, x2, x3, g ^ 1);
        float gv = sel4(p, x1, x2, x3, g ^ 2);
        float ov = sel4(p, x1, x2, x3, g ^ 3);

        // ---- cell update (redundant in all 4 lanes, identical bits) ----
        c = fv * c + iv * gv;
        h = ov * tanh_f(c);

        if (writer) {
            hbuf[(t + 1) & 1][u] = h;        // other buffer than any reader
            if (write_all) hob[(size_t)t * 64] = h;   // fire-and-forget
        }
        asm volatile("s_waitcnt lgkmcnt(0)" ::: "memory");
        __builtin_amdgcn_s_barrier();
        __builtin_amdgcn_sched_barrier(0);
    }
    if (!write_all && writer) *hob = h;
}

// ---------------------------------------------------------------------------
// Final linear: out[b][o] = b_out[o] + sum_j h_last[b][j] * W_out[o][j]
// ---------------------------------------------------------------------------
__global__ __launch_bounds__(256) void final_linear(
    const float* __restrict__ hl,    // [256, 64]
    const float* __restrict__ Wout,  // [2, 64]
    const float* __restrict__ bout,  // [2]
    float* __restrict__ out)         // [256, 2]
{
    __shared__ float w[128];
    int t = threadIdx.x;
    if (t < 128) w[t] = Wout[t];
    __syncthreads();
    const float* h = hl + (size_t)t * 64;
    float a0 = bout[0], a1 = bout[1];
    #pragma unroll 8
    for (int j = 0; j < 64; ++j) {
        float hv = h[j];
        a0 += hv * w[j];
        a1 += hv * w[64 + j];
    }
    out[t * 2 + 0] = a0;
    out[t * 2 + 1] = a1;
}

// ---------------------------------------------------------------------------
extern "C" void kernel_launch(void* const* d_in, const int* in_sizes, int n_in,
                              void* d_out, int out_size, void* d_ws, size_t ws_size,
                              hipStream_t stream)
{
    const float* x     = (const float*)d_in[0];
    const float* W_ih0 = (const float*)d_in[1];
    const float* W_hh0 = (const float*)d_in[2];
    const float* b_ih0 = (const float*)d_in[3];
    const float* b_hh0 = (const float*)d_in[4];
    const float* W_ih1 = (const float*)d_in[5];
    const float* W_hh1 = (const float*)d_in[6];
    const float* b_ih1 = (const float*)d_in[7];
    const float* b_hh1 = (const float*)d_in[8];
    const float* W_ih2 = (const float*)d_in[9];
    const float* W_hh2 = (const float*)d_in[10];
    const float* b_ih2 = (const float*)d_in[11];
    const float* b_hh2 = (const float*)d_in[12];
    const float* W_out = (const float*)d_in[13];
    const float* b_out = (const float*)d_in[14];
    float* out = (float*)d_out;

    const size_t M = (size_t)NB * NT;              // 131072
    const size_t XP_BYTES  = M * H4 * sizeof(float);   // 128 MiB
    const size_t HA_BYTES  = M * 64 * sizeof(float);   // 32 MiB
    const size_t WT0_BYTES = 128 * 256 * sizeof(float);
    const size_t WT1_BYTES = 64 * 256 * sizeof(float);
    const size_t WT2_BYTES = 64 * 256 * sizeof(float);
    const size_t HL_BYTES  = NB * 64 * sizeof(float);
    if (ws_size < XP_BYTES + HA_BYTES + WT0_BYTES + WT1_BYTES + WT2_BYTES + HL_BYTES)
        return;

    char* ws = (char*)d_ws;
    float* XP  = (float*)ws;
    float* HA  = (float*)(ws + XP_BYTES);
    float* WT0 = (float*)(ws + XP_BYTES + HA_BYTES);
    float* WT1 = WT0 + 128 * 256;
    float* WT2 = WT1 + 64 * 256;
    float* HL  = WT2 + 64 * 256;

    transpose_w<<<128, 256, 0, stream>>>(W_ih0, WT0, 128);
    transpose_w<<<64, 256, 0, stream>>>(W_ih1, WT1, 64);
    transpose_w<<<64, 256, 0, stream>>>(W_ih2, WT2, 64);

    const int ngrid = (int)(M / 64);   // 2048

    // Layer 0
    gemm_xp<128><<<ngrid, 256, 0, stream>>>(x, WT0, b_ih0, b_hh0, XP);
    lstm_scan_shfl<<<NB, 256, 0, stream>>>(XP, W_hh0, HA, 1);
    // Layer 1
    gemm_xp<64><<<ngrid, 256, 0, stream>>>(HA, WT1, b_ih1, b_hh1, XP);
    lstm_scan_shfl<<<NB, 256, 0, stream>>>(XP, W_hh1, HA, 1);
    // Layer 2 (only last h needed downstream)
    gemm_xp<64><<<ngrid, 256, 0, stream>>>(HA, WT2, b_ih2, b_hh2, XP);
    lstm_scan_shfl<<<NB, 256, 0, stream>>>(XP, W_hh2, HL, 0);
    // Final projection
    final_linear<<<1, 256, 0, stream>>>(HL, W_out, b_out, out);
}

// Round 4
// 861.282 us; speedup vs baseline: 1.9902x; 1.1759x over previous
//
#include <hip/hip_runtime.h>
#include <cstddef>
#include <cstdint>

// Problem constants (from reference): B=256, T=512, I=128, H=64, 4H=256.
#define NB 256
#define NT 512
#define H4 256

typedef float v2f __attribute__((ext_vector_type(2)));

__device__ __forceinline__ float sigmoid_f(float x) {
    return 1.f / (1.f + __expf(-x));
}
__device__ __forceinline__ float tanh_f(float x) {
    return 2.f / (1.f + __expf(-2.f * x)) - 1.f;
}

// Quad-lane exchange via DPP quad_perm (pure VALU, no LDS pipe):
// xor1: perm(1,0,3,2)=0xB1 ; xor2: perm(2,3,0,1)=0x4E
__device__ __forceinline__ float dpp_xor1(float x) {
    int r = __builtin_amdgcn_update_dpp(0, __float_as_int(x), 0xB1, 0xF, 0xF, true);
    return __int_as_float(r);
}
__device__ __forceinline__ float dpp_xor2(float x) {
    int r = __builtin_amdgcn_update_dpp(0, __float_as_int(x), 0x4E, 0xF, 0xF, true);
    return __int_as_float(r);
}

// ---------------------------------------------------------------------------
// Transpose W [256, K] -> Wt [K, 256] (tiny, once per layer)
// ---------------------------------------------------------------------------
__global__ void transpose_w(const float* __restrict__ W, float* __restrict__ Wt, int K) {
    int idx = blockIdx.x * 256 + threadIdx.x;
    if (idx < 256 * K) {
        int n = idx / K, k = idx - n * K;
        Wt[k * 256 + n] = W[idx];
    }
}

// ---------------------------------------------------------------------------
// Input-projection GEMM (unchanged from round 1 — isolate the scan change)
// ---------------------------------------------------------------------------
template <int K>
__global__ __launch_bounds__(256) void gemm_xp(
    const float* __restrict__ X, const float* __restrict__ Wt,
    const float* __restrict__ b1, const float* __restrict__ b2,
    float* __restrict__ XP)
{
    constexpr int TM = 64;
    constexpr int KC = 16;
    __shared__ __align__(16) float xT[K][TM + 4];
    __shared__ __align__(16) float wc[KC][256];
    const int m0 = blockIdx.x * TM;
    const int t  = threadIdx.x;
    const int cg = (t & 63) * 4;
    const int rg = (t >> 6) * 16;

    for (int idx = t; idx < TM * K; idx += 256) {
        int r = idx / K, k = idx - r * K;
        xT[k][r] = X[(size_t)(m0 + r) * K + k];
    }

    float acc[16][4];
    #pragma unroll
    for (int i = 0; i < 16; ++i)
        #pragma unroll
        for (int j = 0; j < 4; ++j) acc[i][j] = 0.f;

    for (int kc = 0; kc < K; kc += KC) {
        __syncthreads();
        #pragma unroll
        for (int i = 0; i < 4; ++i) {
            int e4 = (t + i * 256) * 4;
            int k = e4 >> 8, n = e4 & 255;
            *(float4*)&wc[k][n] = *(const float4*)&Wt[(size_t)(kc + k) * 256 + n];
        }
        __syncthreads();
        #pragma unroll
        for (int k = 0; k < KC; ++k) {
            float4 w = *(const float4*)&wc[k][cg];
            float xr[16];
            #pragma unroll
            for (int q = 0; q < 4; ++q)
                *(float4*)&xr[q * 4] = *(const float4*)&xT[kc + k][rg + q * 4];
            #pragma unroll
            for (int rr = 0; rr < 16; ++rr) {
                acc[rr][0] += xr[rr] * w.x;
                acc[rr][1] += xr[rr] * w.y;
                acc[rr][2] += xr[rr] * w.z;
                acc[rr][3] += xr[rr] * w.w;
            }
        }
    }

    float bias[4];
    #pragma unroll
    for (int j = 0; j < 4; ++j) bias[j] = b1[cg + j] + b2[cg + j];
    #pragma unroll
    for (int rr = 0; rr < 16; ++rr) {
        float4 o;
        o.x = acc[rr][0] + bias[0];
        o.y = acc[rr][1] + bias[1];
        o.z = acc[rr][2] + bias[2];
        o.w = acc[rr][3] + bias[3];
        *(float4*)&XP[(size_t)(m0 + rg + rr) * 256 + cg] = o;
    }
}

// ---------------------------------------------------------------------------
// LSTM scan v4: K-split quad scheme, 4 waves/block, one block per batch elem.
// Lane = (ks = tid&3  : 16-wide K-slice of h,
//         u  = tid>>2 : hidden unit).
// Each lane holds W_hh[g*64+u][ks*16 .. ks*16+16) for all 4 gates
// (64 weights = 32 v2f). Per step:
//   4x ds_read_b128 (h slice, 2-way bank aliasing = free)
//   -> 32 pk-FMA partial dots (4 gates)
//   -> + xp into gate ks -> 2-stage DPP quad_perm butterfly (VALU only)
//   -> all lanes hold all 4 full pre-activations -> activations + cell
//   (redundant x4, bit-identical) -> ks==0 lane writes h.
// One raw s_barrier per step, lgkmcnt(0) only (no vmcnt drain): xp register
// prefetch (depth 4) and h stores stay in flight across barriers.
// ---------------------------------------------------------------------------
__global__ __launch_bounds__(256) void lstm_scan_quad(
    const float* __restrict__ xp,    // [B*T, 256] gate-major columns
    const float* __restrict__ Whh,   // [256, 64] row-major
    float* __restrict__ hout,        // write_all: [B*T, 64]; else [B, 64]
    int write_all)
{
    const int tid = threadIdx.x;
    const int b = blockIdx.x;
    const int ks = tid & 3;
    const int u = tid >> 2;            // 0..63
    __shared__ __align__(16) float hbuf[2][64];

    // Per-lane weights: gate g, k-slice ks of row g*64+u
    v2f wg[4][8];
    #pragma unroll
    for (int g = 0; g < 4; ++g) {
        const v2f* Wv = (const v2f*)(Whh + (size_t)(g * 64 + u) * 64 + ks * 16);
        #pragma unroll
        for (int j = 0; j < 8; ++j) wg[g][j] = Wv[j];
    }

    if (tid < 64) hbuf[0][tid] = 0.f;
    asm volatile("s_waitcnt lgkmcnt(0)" ::: "memory");
    __builtin_amdgcn_s_barrier();
    __builtin_amdgcn_sched_barrier(0);

    // xp column for gate ks, unit u
    const float* xpb = xp + (size_t)b * NT * H4 + (ks * 64 + u);
    float xr[4];
    #pragma unroll
    for (int d = 0; d < 4; ++d) xr[d] = xpb[(size_t)d * H4];

    float* hob = hout + (write_all ? ((size_t)b * NT * 64 + u)
                                   : ((size_t)b * 64 + u));
    const bool writer = (ks == 0);

    float c = 0.f, h = 0.f;

    #pragma unroll 4
    for (int t = 0; t < NT; ++t) {
        // ---- h k-slice from LDS: 16 floats = 4x ds_read_b128 ----
        const v2f* hv = (const v2f*)&hbuf[t & 1][ks * 16];
        v2f h0 = hv[0], h1 = hv[1], h2 = hv[2], h3 = hv[3];
        v2f h4 = hv[4], h5 = hv[5], h6 = hv[6], h7 = hv[7];

        // ---- partial dots for all 4 gates over this k-slice ----
        float p[4];
        #pragma unroll
        for (int g = 0; g < 4; ++g) {
            v2f a = wg[g][0] * h0 + wg[g][2] * h2;
            v2f bb = wg[g][1] * h1 + wg[g][3] * h3;
            a += wg[g][4] * h4 + wg[g][6] * h6;
            bb += wg[g][5] * h5 + wg[g][7] * h7;
            v2f s = a + bb;
            p[g] = s.x + s.y;
        }

        // xp contribution: this lane's xr is gate ks's xp value (add once)
        float xc = xr[t & 3];
        p[0] += (ks == 0) ? xc : 0.f;
        p[1] += (ks == 1) ? xc : 0.f;
        p[2] += (ks == 2) ? xc : 0.f;
        p[3] += (ks == 3) ? xc : 0.f;

        // refill the just-consumed prefetch slot (t+4), clamped at tail
        { int tn = t + 4; if (tn > NT - 1) tn = NT - 1;
          xr[t & 3] = xpb[(size_t)tn * H4]; }

        // ---- quad butterfly reduce (DPP, pure VALU) ----
        #pragma unroll
        for (int g = 0; g < 4; ++g) p[g] += dpp_xor1(p[g]);
        #pragma unroll
        for (int g = 0; g < 4; ++g) p[g] += dpp_xor2(p[g]);

        // ---- activations + cell update (redundant x4, identical bits) ----
        float iv = sigmoid_f(p[0]);
        float fv = sigmoid_f(p[1]);
        float gv = tanh_f(p[2]);
        float ov = sigmoid_f(p[3]);
        c = fv * c + iv * gv;
        h = ov * tanh_f(c);

        if (writer) {
            hbuf[(t + 1) & 1][u] = h;        // other buffer than any reader
            if (write_all) hob[(size_t)t * 64] = h;   // fire-and-forget
        }
        asm volatile("s_waitcnt lgkmcnt(0)" ::: "memory");
        __builtin_amdgcn_s_barrier();
        __builtin_amdgcn_sched_barrier(0);
    }
    if (!write_all && writer) *hob = h;
}

// ---------------------------------------------------------------------------
// Final linear: out[b][o] = b_out[o] + sum_j h_last[b][j] * W_out[o][j]
// ---------------------------------------------------------------------------
__global__ __launch_bounds__(256) void final_linear(
    const float* __restrict__ hl,    // [256, 64]
    const float* __restrict__ Wout,  // [2, 64]
    const float* __restrict__ bout,  // [2]
    float* __restrict__ out)         // [256, 2]
{
    __shared__ float w[128];
    int t = threadIdx.x;
    if (t < 128) w[t] = Wout[t];
    __syncthreads();
    const float* h = hl + (size_t)t * 64;
    float a0 = bout[0], a1 = bout[1];
    #pragma unroll 8
    for (int j = 0; j < 64; ++j) {
        float hv = h[j];
        a0 += hv * w[j];
        a1 += hv * w[64 + j];
    }
    out[t * 2 + 0] = a0;
    out[t * 2 + 1] = a1;
}

// ---------------------------------------------------------------------------
extern "C" void kernel_launch(void* const* d_in, const int* in_sizes, int n_in,
                              void* d_out, int out_size, void* d_ws, size_t ws_size,
                              hipStream_t stream)
{
    const float* x     = (const float*)d_in[0];
    const float* W_ih0 = (const float*)d_in[1];
    const float* W_hh0 = (const float*)d_in[2];
    const float* b_ih0 = (const float*)d_in[3];
    const float* b_hh0 = (const float*)d_in[4];
    const float* W_ih1 = (const float*)d_in[5];
    const float* W_hh1 = (const float*)d_in[6];
    const float* b_ih1 = (const float*)d_in[7];
    const float* b_hh1 = (const float*)d_in[8];
    const float* W_ih2 = (const float*)d_in[9];
    const float* W_hh2 = (const float*)d_in[10];
    const float* b_ih2 = (const float*)d_in[11];
    const float* b_hh2 = (const float*)d_in[12];
    const float* W_out = (const float*)d_in[13];
    const float* b_out = (const float*)d_in[14];
    float* out = (float*)d_out;

    const size_t M = (size_t)NB * NT;              // 131072
    const size_t XP_BYTES  = M * H4 * sizeof(float);   // 128 MiB
    const size_t HA_BYTES  = M * 64 * sizeof(float);   // 32 MiB
    const size_t WT0_BYTES = 128 * 256 * sizeof(float);
    const size_t WT1_BYTES = 64 * 256 * sizeof(float);
    const size_t WT2_BYTES = 64 * 256 * sizeof(float);
    const size_t HL_BYTES  = NB * 64 * sizeof(float);
    if (ws_size < XP_BYTES + HA_BYTES + WT0_BYTES + WT1_BYTES + WT2_BYTES + HL_BYTES)
        return;

    char* ws = (char*)d_ws;
    float* XP  = (float*)ws;
    float* HA  = (float*)(ws + XP_BYTES);
    float* WT0 = (float*)(ws + XP_BYTES + HA_BYTES);
    float* WT1 = WT0 + 128 * 256;
    float* WT2 = WT1 + 64 * 256;
    float* HL  = WT2 + 64 * 256;

    transpose_w<<<128, 256, 0, stream>>>(W_ih0, WT0, 128);
    transpose_w<<<64, 256, 0, stream>>>(W_ih1, WT1, 64);
    transpose_w<<<64, 256, 0, stream>>>(W_ih2, WT2, 64);

    const int ngrid = (int)(M / 64);   // 2048

    // Layer 0
    gemm_xp<128><<<ngrid, 256, 0, stream>>>(x, WT0, b_ih0, b_hh0, XP);
    lstm_scan_quad<<<NB, 256, 0, stream>>>(XP, W_hh0, HA, 1);
    // Layer 1
    gemm_xp<64><<<ngrid, 256, 0, stream>>>(HA, WT1, b_ih1, b_hh1, XP);
    lstm_scan_quad<<<NB, 256, 0, stream>>>(XP, W_hh1, HA, 1);
    // Layer 2 (only last h needed downstream)
    gemm_xp<64><<<ngrid, 256, 0, stream>>>(HA, WT2, b_ih2, b_hh2, XP);
    lstm_scan_quad<<<NB, 256, 0, stream>>>(XP, W_hh2, HL, 0);
    // Final projection
    final_linear<<<1, 256, 0, stream>>>(HL, W_out, b_out, out);
}

// Round 5
// 734.389 us; speedup vs baseline: 2.3341x; 1.1728x over previous
//
#include <hip/hip_runtime.h>
#include <cstddef>
#include <cstdint>

// Problem constants (from reference): B=256, T=512, I=128, H=64, 4H=256.
#define NB 256
#define NT 512
#define H4 256

typedef float v2f __attribute__((ext_vector_type(2)));

// Quad-lane exchange via DPP quad_perm (pure VALU, no LDS pipe):
// xor1: perm(1,0,3,2)=0xB1 ; xor2: perm(2,3,0,1)=0x4E
__device__ __forceinline__ float dpp_xor1(float x) {
    int r = __builtin_amdgcn_update_dpp(0, __float_as_int(x), 0xB1, 0xF, 0xF, true);
    return __int_as_float(r);
}
__device__ __forceinline__ float dpp_xor2(float x) {
    int r = __builtin_amdgcn_update_dpp(0, __float_as_int(x), 0x4E, 0xF, 0xF, true);
    return __int_as_float(r);
}

// returns x[m] for runtime m (2-level cndmask)
__device__ __forceinline__ float sel4(float x0, float x1, float x2, float x3, int m) {
    float lo = (m & 1) ? x1 : x0;
    float hi = (m & 1) ? x3 : x2;
    return (m & 2) ? hi : lo;
}

// ---------------------------------------------------------------------------
// Transpose W [256, K] -> Wt [K, 256] (tiny, once per layer)
// ---------------------------------------------------------------------------
__global__ void transpose_w(const float* __restrict__ W, float* __restrict__ Wt, int K) {
    int idx = blockIdx.x * 256 + threadIdx.x;
    if (idx < 256 * K) {
        int n = idx / K, k = idx - n * K;
        Wt[k * 256 + n] = W[idx];
    }
}

// ---------------------------------------------------------------------------
// Input-projection GEMM (unchanged — already near f32 vector roofline)
// ---------------------------------------------------------------------------
template <int K>
__global__ __launch_bounds__(256) void gemm_xp(
    const float* __restrict__ X, const float* __restrict__ Wt,
    const float* __restrict__ b1, const float* __restrict__ b2,
    float* __restrict__ XP)
{
    constexpr int TM = 64;
    constexpr int KC = 16;
    __shared__ __align__(16) float xT[K][TM + 4];
    __shared__ __align__(16) float wc[KC][256];
    const int m0 = blockIdx.x * TM;
    const int t  = threadIdx.x;
    const int cg = (t & 63) * 4;
    const int rg = (t >> 6) * 16;

    for (int idx = t; idx < TM * K; idx += 256) {
        int r = idx / K, k = idx - r * K;
        xT[k][r] = X[(size_t)(m0 + r) * K + k];
    }

    float acc[16][4];
    #pragma unroll
    for (int i = 0; i < 16; ++i)
        #pragma unroll
        for (int j = 0; j < 4; ++j) acc[i][j] = 0.f;

    for (int kc = 0; kc < K; kc += KC) {
        __syncthreads();
        #pragma unroll
        for (int i = 0; i < 4; ++i) {
            int e4 = (t + i * 256) * 4;
            int k = e4 >> 8, n = e4 & 255;
            *(float4*)&wc[k][n] = *(const float4*)&Wt[(size_t)(kc + k) * 256 + n];
        }
        __syncthreads();
        #pragma unroll
        for (int k = 0; k < KC; ++k) {
            float4 w = *(const float4*)&wc[k][cg];
            float xr[16];
            #pragma unroll
            for (int q = 0; q < 4; ++q)
                *(float4*)&xr[q * 4] = *(const float4*)&xT[kc + k][rg + q * 4];
            #pragma unroll
            for (int rr = 0; rr < 16; ++rr) {
                acc[rr][0] += xr[rr] * w.x;
                acc[rr][1] += xr[rr] * w.y;
                acc[rr][2] += xr[rr] * w.z;
                acc[rr][3] += xr[rr] * w.w;
            }
        }
    }

    float bias[4];
    #pragma unroll
    for (int j = 0; j < 4; ++j) bias[j] = b1[cg + j] + b2[cg + j];
    #pragma unroll
    for (int rr = 0; rr < 16; ++rr) {
        float4 o;
        o.x = acc[rr][0] + bias[0];
        o.y = acc[rr][1] + bias[1];
        o.z = acc[rr][2] + bias[2];
        o.w = acc[rr][3] + bias[3];
        *(float4*)&XP[(size_t)(m0 + rg + rr) * 256 + cg] = o;
    }
}

// ---------------------------------------------------------------------------
// LSTM scan v5: quad k-split with XOR-permuted gate ownership.
// Lane = (ks = tid&3 : 16-wide K-slice AND owned gate, u = tid>>2 : unit).
// Lane ks holds slot-j weights for gate (ks^j) over k-slice ks -> its
// partial p[j] is XOR-indexed, so reduce-scatter is a uniform DPP pattern:
//   S = p[0] + dpp1(p[1]) + dpp2(p[2]) + dpp2(dpp1(p[3]))   (gate ks, full K)
// ONE activation chain per lane (branchless via per-lane M/A/B consts:
// act = A*rcp(1+exp2(-pre*M))+B gives sigmoid or tanh), then 3-DPP allgather
// + cndmask selects for the cell update (redundant x4, bit-identical).
// One raw s_barrier per step, lgkmcnt(0) only (no vmcnt drain).
// ---------------------------------------------------------------------------
__global__ __launch_bounds__(256) void lstm_scan_xor(
    const float* __restrict__ xp,    // [B*T, 256] gate-major columns
    const float* __restrict__ Whh,   // [256, 64] row-major
    float* __restrict__ hout,        // write_all: [B*T, 64]; else [B, 64]
    int write_all)
{
    const int tid = threadIdx.x;
    const int b = blockIdx.x;
    const int ks = tid & 3;
    const int u = tid >> 2;            // 0..63
    __shared__ __align__(16) float hbuf[2][64];

    // XOR-permuted per-lane weights: slot j = gate (ks^j), k-slice ks
    v2f wg[4][8];
    #pragma unroll
    for (int j = 0; j < 4; ++j) {
        const v2f* Wv = (const v2f*)(Whh + (size_t)(((ks ^ j) * 64) + u) * 64 + ks * 16);
        #pragma unroll
        for (int q = 0; q < 8; ++q) wg[j][q] = Wv[q];
    }

    // Per-lane activation constants: gate 2 (j=0 slot of lane ks=2) is tanh.
    const float LOG2E = 1.4426950408889634f;
    const float M = (ks == 2) ? (2.f * LOG2E) : LOG2E;
    const float A = (ks == 2) ? 2.f : 1.f;
    const float Bc = (ks == 2) ? -1.f : 0.f;

    if (tid < 64) hbuf[0][tid] = 0.f;
    asm volatile("s_waitcnt lgkmcnt(0)" ::: "memory");
    __builtin_amdgcn_s_barrier();
    __builtin_amdgcn_sched_barrier(0);

    // xp column for gate ks, unit u
    const float* xpb = xp + (size_t)b * NT * H4 + (ks * 64 + u);
    float xr[4];
    #pragma unroll
    for (int d = 0; d < 4; ++d) xr[d] = xpb[(size_t)d * H4];

    float* hob = hout + (write_all ? ((size_t)b * NT * 64 + u)
                                   : ((size_t)b * 64 + u));
    const bool writer = (ks == 0);

    float c = 0.f, h = 0.f;

    #pragma unroll 4
    for (int t = 0; t < NT; ++t) {
        // ---- h k-slice from LDS: 16 floats = 4x ds_read_b128 (broadcast) ----
        const v2f* hv = (const v2f*)&hbuf[t & 1][ks * 16];
        v2f h0 = hv[0], h1 = hv[1], h2 = hv[2], h3 = hv[3];
        v2f h4 = hv[4], h5 = hv[5], h6 = hv[6], h7 = hv[7];

        // ---- partial dots, slot j = gate ks^j over this k-slice ----
        float p[4];
        #pragma unroll
        for (int j = 0; j < 4; ++j) {
            v2f s0 = wg[j][0] * h0 + wg[j][2] * h2;
            v2f s1 = wg[j][1] * h1 + wg[j][3] * h3;
            s0 += wg[j][4] * h4 + wg[j][6] * h6;
            s1 += wg[j][5] * h5 + wg[j][7] * h7;
            v2f s = s0 + s1;
            p[j] = s.x + s.y;
        }

        // refill the just-consumed prefetch slot (t+4), clamped at tail
        { int tn = t + 4; if (tn > NT - 1) tn = NT - 1;
          float xnew = xpb[(size_t)tn * H4];
          // use current slot value first:
          float xc = xr[t & 3];
          xr[t & 3] = xnew;

          // ---- reduce-scatter: full pre-activation of OWN gate ks ----
          float S = p[0] + dpp_xor1(p[1]);
          float t3 = dpp_xor2(dpp_xor1(p[3]));
          S += dpp_xor2(p[2]) + t3;
          float pre = S + xc;

          // ---- single branchless activation chain ----
          float e = __builtin_amdgcn_exp2f(-(pre * M));
          float y = __builtin_amdgcn_rcpf(1.f + e);
          float act = __builtin_fmaf(A, y, Bc);

          // ---- allgather activations across the quad ----
          float a1 = dpp_xor1(act);   // gate ks^1
          float a2 = dpp_xor2(act);   // gate ks^2
          float a3 = dpp_xor2(a1);    // gate ks^3

          // gate extraction: i=gate0, f=gate1, g=gate2, o=gate3
          float ig = (ks & 1) ? (a1 * a3) : (act * a2);   // i*g
          float fv = sel4(a1, act, a3, a2, ks);           // f
          float ov = sel4(a3, a2, a1, act, ks);           // o

          // ---- cell update (redundant x4, identical bits) ----
          c = __builtin_fmaf(fv, c, ig);
          float e2 = __builtin_amdgcn_exp2f(-(c * (2.f * LOG2E)));
          float y2 = __builtin_amdgcn_rcpf(1.f + e2);
          float th = __builtin_fmaf(2.f, y2, -1.f);
          h = ov * th;
        }

        if (writer) {
            hbuf[(t + 1) & 1][u] = h;        // other buffer than any reader
            if (write_all) hob[(size_t)t * 64] = h;   // fire-and-forget
        }
        asm volatile("s_waitcnt lgkmcnt(0)" ::: "memory");
        __builtin_amdgcn_s_barrier();
        __builtin_amdgcn_sched_barrier(0);
    }
    if (!write_all && writer) *hob = h;
}

// ---------------------------------------------------------------------------
// Final linear: out[b][o] = b_out[o] + sum_j h_last[b][j] * W_out[o][j]
// ---------------------------------------------------------------------------
__global__ __launch_bounds__(256) void final_linear(
    const float* __restrict__ hl,    // [256, 64]
    const float* __restrict__ Wout,  // [2, 64]
    const float* __restrict__ bout,  // [2]
    float* __restrict__ out)         // [256, 2]
{
    __shared__ float w[128];
    int t = threadIdx.x;
    if (t < 128) w[t] = Wout[t];
    __syncthreads();
    const float* h = hl + (size_t)t * 64;
    float a0 = bout[0], a1 = bout[1];
    #pragma unroll 8
    for (int j = 0; j < 64; ++j) {
        float hv = h[j];
        a0 += hv * w[j];
        a1 += hv * w[64 + j];
    }
    out[t * 2 + 0] = a0;
    out[t * 2 + 1] = a1;
}

// ---------------------------------------------------------------------------
extern "C" void kernel_launch(void* const* d_in, const int* in_sizes, int n_in,
                              void* d_out, int out_size, void* d_ws, size_t ws_size,
                              hipStream_t stream)
{
    const float* x     = (const float*)d_in[0];
    const float* W_ih0 = (const float*)d_in[1];
    const float* W_hh0 = (const float*)d_in[2];
    const float* b_ih0 = (const float*)d_in[3];
    const float* b_hh0 = (const float*)d_in[4];
    const float* W_ih1 = (const float*)d_in[5];
    const float* W_hh1 = (const float*)d_in[6];
    const float* b_ih1 = (const float*)d_in[7];
    const float* b_hh1 = (const float*)d_in[8];
    const float* W_ih2 = (const float*)d_in[9];
    const float* W_hh2 = (const float*)d_in[10];
    const float* b_ih2 = (const float*)d_in[11];
    const float* b_hh2 = (const float*)d_in[12];
    const float* W_out = (const float*)d_in[13];
    const float* b_out = (const float*)d_in[14];
    float* out = (float*)d_out;

    const size_t M = (size_t)NB * NT;              // 131072
    const size_t XP_BYTES  = M * H4 * sizeof(float);   // 128 MiB
    const size_t HA_BYTES  = M * 64 * sizeof(float);   // 32 MiB
    const size_t WT0_BYTES = 128 * 256 * sizeof(float);
    const size_t WT1_BYTES = 64 * 256 * sizeof(float);
    const size_t WT2_BYTES = 64 * 256 * sizeof(float);
    const size_t HL_BYTES  = NB * 64 * sizeof(float);
    if (ws_size < XP_BYTES + HA_BYTES + WT0_BYTES + WT1_BYTES + WT2_BYTES + HL_BYTES)
        return;

    char* ws = (char*)d_ws;
    float* XP  = (float*)ws;
    float* HA  = (float*)(ws + XP_BYTES);
    float* WT0 = (float*)(ws + XP_BYTES + HA_BYTES);
    float* WT1 = WT0 + 128 * 256;
    float* WT2 = WT1 + 64 * 256;
    float* HL  = WT2 + 64 * 256;

    transpose_w<<<128, 256, 0, stream>>>(W_ih0, WT0, 128);
    transpose_w<<<64, 256, 0, stream>>>(W_ih1, WT1, 64);
    transpose_w<<<64, 256, 0, stream>>>(W_ih2, WT2, 64);

    const int ngrid = (int)(M / 64);   // 2048

    // Layer 0
    gemm_xp<128><<<ngrid, 256, 0, stream>>>(x, WT0, b_ih0, b_hh0, XP);
    lstm_scan_xor<<<NB, 256, 0, stream>>>(XP, W_hh0, HA, 1);
    // Layer 1
    gemm_xp<64><<<ngrid, 256, 0, stream>>>(HA, WT1, b_ih1, b_hh1, XP);
    lstm_scan_xor<<<NB, 256, 0, stream>>>(XP, W_hh1, HA, 1);
    // Layer 2 (only last h needed downstream)
    gemm_xp<64><<<ngrid, 256, 0, stream>>>(HA, WT2, b_ih2, b_hh2, XP);
    lstm_scan_xor<<<NB, 256, 0, stream>>>(XP, W_hh2, HL, 0);
    // Final projection
    final_linear<<<1, 256, 0, stream>>>(HL, W_out, b_out, out);
}